// Round 7
// baseline (130.326 us; speedup 1.0000x reference)
//
#include <hip/hip_runtime.h>

typedef unsigned short u16;
typedef u16 u16x4 __attribute__((ext_vector_type(4)));
typedef u16 u16x8 __attribute__((ext_vector_type(8)));
typedef __bf16 bf16x8 __attribute__((ext_vector_type(8)));
typedef float f32x4 __attribute__((ext_vector_type(4)));

#define DEVINL static __device__ __forceinline__

DEVINL u16 f2bf(float f) {
    unsigned u = __builtin_bit_cast(unsigned, f);
    u += 0x7fff + ((u >> 16) & 1);           // RNE
    return (u16)(u >> 16);
}

DEVINL u16 pbf(float f) {                    // round-half-up, for P in [0, 2^8]
    unsigned u = __builtin_bit_cast(unsigned, f);
    return (u16)((u + 0x8000) >> 16);
}

DEVINL f32x4 mfma_bf16(u16x8 a, u16x8 b, f32x4 c) {
    return __builtin_amdgcn_mfma_f32_16x16x32_bf16(
        __builtin_bit_cast(bf16x8, a), __builtin_bit_cast(bf16x8, b), c, 0, 0, 0);
}

DEVINL void gload16(const void* g, void* lds) {
    __builtin_amdgcn_global_load_lds(
        (const __attribute__((address_space(1))) void*)g,
        (__attribute__((address_space(3))) void*)lds, 16, 0, 0);
}

// ---------------- conversion / transpose kernels ----------------

__global__ void cvt_x_kernel(const float4* __restrict__ x4, u16x4* __restrict__ o4) {
    int idx = blockIdx.x * 256 + threadIdx.x;
    float4 a = x4[idx];
    u16x4 o;
    o[0] = f2bf(a.x); o[1] = f2bf(a.y); o[2] = f2bf(a.z); o[3] = f2bf(a.w);
    o4[idx] = o;
}

__global__ void fill_bias(const float* __restrict__ bq, const float* __restrict__ bk,
                          const float* __restrict__ bv, float* __restrict__ dst) {
    int i = blockIdx.x * 256 + threadIdx.x;
    if (i < 1024) dst[i] = bq[i];
    else if (i < 1280) dst[i] = bk[i - 1024];
    else if (i < 1536) dst[i] = bv[i - 1280];
}

// src fp32 [1024][N] -> dst bf16 [(rowOff+n)][1024]
__global__ void twt_kernel(const float* __restrict__ src, u16* __restrict__ dst,
                           int N, int rowOff) {
    __shared__ float t[64][65];
    int k0 = blockIdx.x * 64, n0 = blockIdx.y * 64;
    int tid = threadIdx.x;
#pragma unroll
    for (int j = 0; j < 16; j++) {
        int idx = j * 256 + tid; int r = idx >> 6, c = idx & 63;
        t[r][c] = src[(size_t)(k0 + r) * N + n0 + c];
    }
    __syncthreads();
#pragma unroll
    for (int j = 0; j < 16; j++) {
        int idx = j * 256 + tid; int r = idx >> 6, c = idx & 63;
        dst[(size_t)(rowOff + n0 + r) * 1024 + k0 + c] = f2bf(t[c][r]);
    }
}

// qkv bf16 [8192][1536] V-section -> vt bf16 [(b*4+h)*64+hd][4096]
__global__ void tv_kernel(const u16* __restrict__ qkv, u16* __restrict__ vt) {
    __shared__ u16 t[64][68];
    int t0 = blockIdx.x * 64; int h = blockIdx.y; int b = blockIdx.z;
    int tid = threadIdx.x;
#pragma unroll
    for (int j = 0; j < 16; j++) {
        int idx = j * 256 + tid; int r = idx >> 6, c = idx & 63;
        t[r][c] = qkv[(size_t)(b * 4096 + t0 + r) * 1536 + 1280 + h * 64 + c];
    }
    __syncthreads();
#pragma unroll
    for (int j = 0; j < 16; j++) {
        int idx = j * 256 + tid; int r = idx >> 6, c = idx & 63;
        vt[(size_t)((b * 4 + h) * 64 + r) * 4096 + t0 + c] = t[c][r];
    }
}

// ---------------- MFMA GEMM: C[M][N] = (A[M][K] * Bt[N][K]^T + bias) * colscale ----------------
// Bijective chunked XCD swizzle (m204) kept: R6 A/B showed ~10us off the GEMM phase.

template <bool F32OUT>
__global__ __launch_bounds__(256, 2) void gemm_bt(
    const u16* __restrict__ A, const u16* __restrict__ Bt, void* __restrict__ Cp,
    const float* __restrict__ bias, int M, int N, int K, int qn, float qscale) {
    __shared__ __align__(16) u16 As[128 * 64];
    __shared__ __align__(16) u16 Bs[128 * 64];
    int tid = threadIdx.x; int l = tid & 63; int w = tid >> 6;

    int nwg = gridDim.x * gridDim.y;
    int lin = blockIdx.y * gridDim.x + blockIdx.x;
    int q_ = nwg >> 3, r_ = nwg & 7;
    int xcd = lin & 7, i_ = lin >> 3;
    int wgid = (xcd < r_ ? xcd * (q_ + 1) : r_ * (q_ + 1) + (xcd - r_) * q_) + i_;
    int m0 = (wgid / gridDim.x) * 128, n0 = (wgid % gridDim.x) * 128;

    int wm = (w >> 1) * 64, wn = (w & 1) * 64;
    f32x4 acc[4][4] = {};

    int srow[4], scol[4];
#pragma unroll
    for (int c = 0; c < 4; c++) {
        int b = (w * 4 + c) * 1024 + l * 16;
        int row = b >> 7, inner = b & 127;
        srow[c] = row;
        scol[c] = (inner ^ ((row & 7) << 4)) >> 1;
    }
    int nk = K >> 6;
    for (int kt = 0; kt < nk; ++kt) {
        int kb = kt << 6;
#pragma unroll
        for (int c = 0; c < 4; c++) {
            gload16(A + (size_t)(m0 + srow[c]) * K + kb + scol[c], (char*)As + (w * 4 + c) * 1024);
            gload16(Bt + (size_t)(n0 + srow[c]) * K + kb + scol[c], (char*)Bs + (w * 4 + c) * 1024);
        }
        __syncthreads();
#pragma unroll
        for (int kc = 0; kc < 2; ++kc) {
            int co = (kc * 32 + (l >> 4) * 8) * 2;
            u16x8 af[4], bf[4];
#pragma unroll
            for (int mf = 0; mf < 4; ++mf) {
                int row = wm + mf * 16 + (l & 15);
                af[mf] = *(const u16x8*)((const char*)As + row * 128 + (co ^ ((row & 7) << 4)));
            }
#pragma unroll
            for (int nf = 0; nf < 4; ++nf) {
                int row = wn + nf * 16 + (l & 15);
                bf[nf] = *(const u16x8*)((const char*)Bs + row * 128 + (co ^ ((row & 7) << 4)));
            }
#pragma unroll
            for (int mf = 0; mf < 4; ++mf)
#pragma unroll
                for (int nf = 0; nf < 4; ++nf)
                    acc[mf][nf] = mfma_bf16(af[mf], bf[nf], acc[mf][nf]);
        }
        __syncthreads();
    }
#pragma unroll
    for (int mf = 0; mf < 4; ++mf) {
#pragma unroll
        for (int nf = 0; nf < 4; ++nf) {
            int col = n0 + wn + nf * 16 + (l & 15);
            float bv = bias ? bias[col] : 0.0f;
            float scl = (col < qn) ? qscale : 1.0f;   // uniform per 16-lane group
#pragma unroll
            for (int r = 0; r < 4; r++) {
                int row = m0 + wm + mf * 16 + (l >> 4) * 4 + r;
                float v = (acc[mf][nf][r] + bv) * scl;
                if (F32OUT) ((float*)Cp)[(size_t)row * N + col] = v;
                else        ((u16*)Cp)[(size_t)row * N + col] = f2bf(v);
            }
        }
    }
}

// ---------------- banded GQA flash attention ----------------
// TLP round: block = (qblock 64, head-pair, b); grid 64x8x2 = 1024 blocks = 4/CU.
// 8 waves = 2 q-heads x 4 q-fragments (16 rows each). LDS 32KB, VGPR<=64 ->
// up to 8 waves/SIMD. Single-buffer 2-barrier loop (R5 structure: beats both
// explicit-pipeline variants R4/R6). Q pre-scaled to log2 domain in QKV GEMM.

__global__ __launch_bounds__(512, 8) void attn_kernel(
    const u16* __restrict__ qkv, const u16* __restrict__ vt, u16* __restrict__ y) {
    __shared__ __align__(16) u16 Ks[64 * 64];
    __shared__ __align__(16) u16 Vs[64 * 64];
    __shared__ __align__(16) u16 Ps[8][16 * 64];
    int tid = threadIdx.x, l = tid & 63, w = tid >> 6;
    // XCD-locality remap: same-XCD blocks (bid%8 fixed) get 8 consecutive qb
    int qb = ((blockIdx.x & 7) << 3) | (blockIdx.x >> 3);
    int h = blockIdx.y >> 1, hp = blockIdx.y & 1, b = blockIdx.z;
    int qstart = qb * 64;
    size_t rowbase = (size_t)b * 4096;
    int hq = h * 4 + hp * 2 + (w >> 2);      // this wave's q-head
    int qrow0 = (w & 3) * 16;                // wave's 16 q-rows within qblock

    // Q fragment (16 rows, K=64 over 2 chunks); Q already scaled to log2 domain
    u16x8 qf_[2];
#pragma unroll
    for (int kc = 0; kc < 2; ++kc)
        qf_[kc] = *(const u16x8*)(qkv + (rowbase + qstart + qrow0 + (l & 15)) * 1536
                                  + hq * 64 + kc * 32 + (l >> 4) * 8);

    f32x4 o[4] = {};
    float mrow = -__builtin_inff(), srow_ = 0.f;

    const u16* kbase_ptr = qkv + 1024 + h * 64;
    const u16* vbase_ptr = vt + (size_t)((b * 4 + h) * 64) * 4096;

    // per-wave staging chunk (1 KiB each for K and V), pre-swizzled source
    int sb_ = w * 1024 + l * 16;
    int g_row = sb_ >> 7, g_inner = sb_ & 127;
    int g_col = (g_inner ^ ((g_row & 7) << 4)) >> 1;

#pragma unroll
    for (int kstart = qstart - 256; kstart <= qstart + 256; kstart += 64) {
        if (kstart < 0 || kstart >= 4096) continue;
        gload16(kbase_ptr + (rowbase + kstart + g_row) * 1536 + g_col, (char*)Ks + w * 1024);
        gload16(vbase_ptr + (size_t)g_row * 4096 + kstart + g_col, (char*)Vs + w * 1024);
        __syncthreads();

        // S^T[key][q] = K * Q^T  (log2-domain)
        f32x4 st[4] = {};
#pragma unroll
        for (int kc = 0; kc < 2; ++kc) {
            int co = (kc * 32 + (l >> 4) * 8) * 2;
#pragma unroll
            for (int kf = 0; kf < 4; ++kf) {
                int row = kf * 16 + (l & 15);
                u16x8 kfr = *(const u16x8*)((const char*)Ks + row * 128 + (co ^ ((row & 7) << 4)));
                st[kf] = mfma_bf16(kfr, qf_[kc], st[kf]);
            }
        }

        // window masking only needed on the two boundary tiles
        bool mlo = (kstart == qstart - 256);
        bool mhi = (kstart == qstart + 256);

        int qoff = qrow0 + (l & 15);
        float pmax = -1e30f;
        float sv[4][4];
#pragma unroll
        for (int kf = 0; kf < 4; ++kf)
#pragma unroll
            for (int r = 0; r < 4; r++) {
                int koff = kf * 16 + (l >> 4) * 4 + r;
                float v = st[kf][r];
                if (mlo && koff < qoff) v = -1e30f;
                if (mhi && koff > qoff) v = -1e30f;
                sv[kf][r] = v;
                pmax = fmaxf(pmax, v);
            }
        pmax = fmaxf(pmax, __shfl_xor(pmax, 16));
        pmax = fmaxf(pmax, __shfl_xor(pmax, 32));

        // defer-max: skip rescale when growth bounded (P then bounded by 2^8)
        bool resc = !__all(pmax - mrow <= 8.0f);
        float newm = resc ? fmaxf(mrow, pmax) : mrow;
        float psum = 0.f;
#pragma unroll
        for (int kf = 0; kf < 4; ++kf) {
            u16x4 pk;
#pragma unroll
            for (int r = 0; r < 4; r++) {
                float e = __builtin_amdgcn_exp2f(sv[kf][r] - newm);
                psum += e;
                pk[r] = pbf(e);
            }
            int row = l & 15;
            int keyc = kf * 16 + (l >> 4) * 4;
            *(u16x4*)((char*)Ps[w] + ((row * 128 + keyc * 2) ^ ((row & 7) << 4))) = pk;
        }
        psum += __shfl_xor(psum, 16);
        psum += __shfl_xor(psum, 32);
        if (resc) {
            float fs = __builtin_amdgcn_exp2f(mrow - newm);
            srow_ = srow_ * fs + psum;
            mrow = newm;
#pragma unroll
            for (int r = 0; r < 4; r++) {
                float fb = __shfl(fs, (l >> 4) * 4 + r);
#pragma unroll
                for (int nf = 0; nf < 4; ++nf) o[nf][r] *= fb;
            }
        } else {
            srow_ += psum;
        }

        // O += P * V
#pragma unroll
        for (int kc = 0; kc < 2; ++kc) {
            int co = (kc * 32 + (l >> 4) * 8) * 2;
            int prow = l & 15;
            u16x8 pa = *(const u16x8*)((const char*)Ps[w] + ((prow * 128 + co) ^ ((prow & 7) << 4)));
#pragma unroll
            for (int nf = 0; nf < 4; ++nf) {
                int row = nf * 16 + (l & 15);
                u16x8 vb = *(const u16x8*)((const char*)Vs + row * 128 + (co ^ ((row & 7) << 4)));
                o[nf] = mfma_bf16(pa, vb, o[nf]);
            }
        }
        __syncthreads();
    }

    // normalize + store y bf16 [8192][1024]
    float inv = 1.0f / srow_;
#pragma unroll
    for (int r = 0; r < 4; r++) {
        float sb = __shfl(inv, (l >> 4) * 4 + r);
        int row = qstart + qrow0 + (l >> 4) * 4 + r;
#pragma unroll
        for (int nf = 0; nf < 4; ++nf) {
            int col = hq * 64 + nf * 16 + (l & 15);
            y[(rowbase + row) * 1024 + col] = f2bf(o[nf][r] * sb);
        }
    }
}

// ---------------- host launch ----------------

extern "C" void kernel_launch(void* const* d_in, const int* in_sizes, int n_in,
                              void* d_out, int out_size, void* d_ws, size_t ws_size,
                              hipStream_t stream) {
    const float* x  = (const float*)d_in[0];
    const float* wq = (const float*)d_in[1];
    const float* bq = (const float*)d_in[2];
    const float* wk = (const float*)d_in[3];
    const float* bk = (const float*)d_in[4];
    const float* wv = (const float*)d_in[5];
    const float* bv = (const float*)d_in[6];
    const float* wo = (const float*)d_in[7];
    const float* bo = (const float*)d_in[8];
    float* out = (float*)d_out;

    char* p = (char*)d_ws;
    u16* xb     = (u16*)p;   p += (size_t)8192 * 1024 * 2;   // x bf16
    u16* wqkvt  = (u16*)p;   p += (size_t)1536 * 1024 * 2;   // [n][k] bf16 (q,k,v concat)
    u16* wot    = (u16*)p;   p += (size_t)1024 * 1024 * 2;   // wo^T bf16
    float* bqkv = (float*)p; p += 8192;                      // 1536 fp32 (padded)
    u16* qkvb   = (u16*)p;   p += (size_t)8192 * 1536 * 2;   // QKV bf16
    u16* vtb    = (u16*)p;   p += (size_t)512 * 4096 * 2;    // V^T bf16
    u16* yb     = (u16*)p;                                   // attn out bf16

    cvt_x_kernel<<<8192, 256, 0, stream>>>((const float4*)x, (u16x4*)xb);
    fill_bias<<<6, 256, 0, stream>>>(bq, bk, bv, bqkv);
    twt_kernel<<<dim3(16, 16), 256, 0, stream>>>(wq, wqkvt, 1024, 0);
    twt_kernel<<<dim3(16, 4),  256, 0, stream>>>(wk, wqkvt, 256, 1024);
    twt_kernel<<<dim3(16, 4),  256, 0, stream>>>(wv, wqkvt, 256, 1280);
    twt_kernel<<<dim3(16, 16), 256, 0, stream>>>(wo, wot, 1024, 0);

    // Q columns pre-scaled by 0.125*log2(e) so attention scores are in log2 domain
    gemm_bt<false><<<dim3(12, 64), 256, 0, stream>>>(xb, wqkvt, qkvb, bqkv,
                                                     8192, 1536, 1024, 1024, 0.18033688f);
    tv_kernel<<<dim3(64, 4, 2), 256, 0, stream>>>(qkvb, vtb);
    attn_kernel<<<dim3(64, 8, 2), 512, 0, stream>>>(qkvb, vtb, yb);
    gemm_bt<true><<<dim3(8, 64), 256, 0, stream>>>(yb, wot, out, bo,
                                                   8192, 1024, 1024, 0, 1.0f);
}

// Round 8
// 118.765 us; speedup vs baseline: 1.0974x; 1.0974x over previous
//
#include <hip/hip_runtime.h>

typedef unsigned short u16;
typedef u16 u16x4 __attribute__((ext_vector_type(4)));
typedef u16 u16x8 __attribute__((ext_vector_type(8)));
typedef __bf16 bf16x8 __attribute__((ext_vector_type(8)));
typedef float f32x4 __attribute__((ext_vector_type(4)));

#define DEVINL static __device__ __forceinline__

DEVINL u16 f2bf(float f) {
    unsigned u = __builtin_bit_cast(unsigned, f);
    u += 0x7fff + ((u >> 16) & 1);           // RNE
    return (u16)(u >> 16);
}

DEVINL u16 pbf(float f) {                    // round-half-up, for P in [0, 2^8]
    unsigned u = __builtin_bit_cast(unsigned, f);
    return (u16)((u + 0x8000) >> 16);
}

DEVINL f32x4 mfma_bf16(u16x8 a, u16x8 b, f32x4 c) {
    return __builtin_amdgcn_mfma_f32_16x16x32_bf16(
        __builtin_bit_cast(bf16x8, a), __builtin_bit_cast(bf16x8, b), c, 0, 0, 0);
}

DEVINL void gload16(const void* g, void* lds) {
    __builtin_amdgcn_global_load_lds(
        (const __attribute__((address_space(1))) void*)g,
        (__attribute__((address_space(3))) void*)lds, 16, 0, 0);
}

// ---------------- conversion / transpose kernels ----------------

__global__ void cvt_x_kernel(const float4* __restrict__ x4, u16x4* __restrict__ o4) {
    int idx = blockIdx.x * 256 + threadIdx.x;
    float4 a = x4[idx];
    u16x4 o;
    o[0] = f2bf(a.x); o[1] = f2bf(a.y); o[2] = f2bf(a.z); o[3] = f2bf(a.w);
    o4[idx] = o;
}

__global__ void fill_bias(const float* __restrict__ bq, const float* __restrict__ bk,
                          const float* __restrict__ bv, float* __restrict__ dst) {
    int i = blockIdx.x * 256 + threadIdx.x;
    if (i < 1024) dst[i] = bq[i];
    else if (i < 1280) dst[i] = bk[i - 1024];
    else if (i < 1536) dst[i] = bv[i - 1280];
}

// src fp32 [1024][N] -> dst bf16 [(rowOff+n)][1024]
__global__ void twt_kernel(const float* __restrict__ src, u16* __restrict__ dst,
                           int N, int rowOff) {
    __shared__ float t[64][65];
    int k0 = blockIdx.x * 64, n0 = blockIdx.y * 64;
    int tid = threadIdx.x;
#pragma unroll
    for (int j = 0; j < 16; j++) {
        int idx = j * 256 + tid; int r = idx >> 6, c = idx & 63;
        t[r][c] = src[(size_t)(k0 + r) * N + n0 + c];
    }
    __syncthreads();
#pragma unroll
    for (int j = 0; j < 16; j++) {
        int idx = j * 256 + tid; int r = idx >> 6, c = idx & 63;
        dst[(size_t)(rowOff + n0 + r) * 1024 + k0 + c] = f2bf(t[c][r]);
    }
}

// qkv bf16 [8192][1536] V-section -> vt bf16 [(b*4+h)*64+hd][4096]
__global__ void tv_kernel(const u16* __restrict__ qkv, u16* __restrict__ vt) {
    __shared__ u16 t[64][68];
    int t0 = blockIdx.x * 64; int h = blockIdx.y; int b = blockIdx.z;
    int tid = threadIdx.x;
#pragma unroll
    for (int j = 0; j < 16; j++) {
        int idx = j * 256 + tid; int r = idx >> 6, c = idx & 63;
        t[r][c] = qkv[(size_t)(b * 4096 + t0 + r) * 1536 + 1280 + h * 64 + c];
    }
    __syncthreads();
#pragma unroll
    for (int j = 0; j < 16; j++) {
        int idx = j * 256 + tid; int r = idx >> 6, c = idx & 63;
        vt[(size_t)((b * 4 + h) * 64 + r) * 4096 + t0 + c] = t[c][r];
    }
}

// ---------------- MFMA GEMM: C[M][N] = (A[M][K] * Bt[N][K]^T + bias) * colscale ----------------
// Bijective chunked XCD swizzle (m204): ~10us win measured R5->R6 on the GEMM phase.
// launch_bounds (256,3): 3 blocks/CU (m97 reference: 164 VGPR @ 3 blocks/CU, 874 TF).

template <bool F32OUT>
__global__ __launch_bounds__(256, 3) void gemm_bt(
    const u16* __restrict__ A, const u16* __restrict__ Bt, void* __restrict__ Cp,
    const float* __restrict__ bias, int M, int N, int K, int qn, float qscale) {
    __shared__ __align__(16) u16 As[128 * 64];
    __shared__ __align__(16) u16 Bs[128 * 64];
    int tid = threadIdx.x; int l = tid & 63; int w = tid >> 6;

    int nwg = gridDim.x * gridDim.y;
    int lin = blockIdx.y * gridDim.x + blockIdx.x;
    int q_ = nwg >> 3, r_ = nwg & 7;
    int xcd = lin & 7, i_ = lin >> 3;
    int wgid = (xcd < r_ ? xcd * (q_ + 1) : r_ * (q_ + 1) + (xcd - r_) * q_) + i_;
    int m0 = (wgid / gridDim.x) * 128, n0 = (wgid % gridDim.x) * 128;

    int wm = (w >> 1) * 64, wn = (w & 1) * 64;
    f32x4 acc[4][4] = {};

    int srow[4], scol[4];
#pragma unroll
    for (int c = 0; c < 4; c++) {
        int b = (w * 4 + c) * 1024 + l * 16;
        int row = b >> 7, inner = b & 127;
        srow[c] = row;
        scol[c] = (inner ^ ((row & 7) << 4)) >> 1;
    }
    int nk = K >> 6;
    for (int kt = 0; kt < nk; ++kt) {
        int kb = kt << 6;
#pragma unroll
        for (int c = 0; c < 4; c++) {
            gload16(A + (size_t)(m0 + srow[c]) * K + kb + scol[c], (char*)As + (w * 4 + c) * 1024);
            gload16(Bt + (size_t)(n0 + srow[c]) * K + kb + scol[c], (char*)Bs + (w * 4 + c) * 1024);
        }
        __syncthreads();
#pragma unroll
        for (int kc = 0; kc < 2; ++kc) {
            int co = (kc * 32 + (l >> 4) * 8) * 2;
            u16x8 af[4], bf[4];
#pragma unroll
            for (int mf = 0; mf < 4; ++mf) {
                int row = wm + mf * 16 + (l & 15);
                af[mf] = *(const u16x8*)((const char*)As + row * 128 + (co ^ ((row & 7) << 4)));
            }
#pragma unroll
            for (int nf = 0; nf < 4; ++nf) {
                int row = wn + nf * 16 + (l & 15);
                bf[nf] = *(const u16x8*)((const char*)Bs + row * 128 + (co ^ ((row & 7) << 4)));
            }
#pragma unroll
            for (int mf = 0; mf < 4; ++mf)
#pragma unroll
                for (int nf = 0; nf < 4; ++nf)
                    acc[mf][nf] = mfma_bf16(af[mf], bf[nf], acc[mf][nf]);
        }
        __syncthreads();
    }
#pragma unroll
    for (int mf = 0; mf < 4; ++mf) {
#pragma unroll
        for (int nf = 0; nf < 4; ++nf) {
            int col = n0 + wn + nf * 16 + (l & 15);
            float bv = bias ? bias[col] : 0.0f;
            float scl = (col < qn) ? qscale : 1.0f;   // uniform per 16-lane group
#pragma unroll
            for (int r = 0; r < 4; r++) {
                int row = m0 + wm + mf * 16 + (l >> 4) * 4 + r;
                float v = (acc[mf][nf][r] + bv) * scl;
                if (F32OUT) ((float*)Cp)[(size_t)row * N + col] = v;
                else        ((u16*)Cp)[(size_t)row * N + col] = f2bf(v);
            }
        }
    }
}

// ---------------- banded GQA flash attention ----------------
// block = (qblock 64, head-pair, b); grid 64x8x2 = 1024 blocks = 4/CU.
// 8 waves = 2 q-heads x 4 q-fragments (16 rows each). LDS 32KB.
// launch_bounds (512,4): VGPR cap ~128 (kernel needs ~70) -> NO SPILLS, 4 blocks/CU
// (R7's (512,8) forced 32 VGPR -> scratch spill disaster: WRITE_SIZE 70MB).
// Single-buffer 2-barrier loop (R5 structure). Q pre-scaled to log2 domain.

__global__ __launch_bounds__(512, 4) void attn_kernel(
    const u16* __restrict__ qkv, const u16* __restrict__ vt, u16* __restrict__ y) {
    __shared__ __align__(16) u16 Ks[64 * 64];
    __shared__ __align__(16) u16 Vs[64 * 64];
    __shared__ __align__(16) u16 Ps[8][16 * 64];
    int tid = threadIdx.x, l = tid & 63, w = tid >> 6;
    // XCD-locality remap: same-XCD blocks (bid%8 fixed) get 8 consecutive qb
    int qb = ((blockIdx.x & 7) << 3) | (blockIdx.x >> 3);
    int h = blockIdx.y >> 1, hp = blockIdx.y & 1, b = blockIdx.z;
    int qstart = qb * 64;
    size_t rowbase = (size_t)b * 4096;
    int hq = h * 4 + hp * 2 + (w >> 2);      // this wave's q-head
    int qrow0 = (w & 3) * 16;                // wave's 16 q-rows within qblock

    // Q fragment (16 rows, K=64 over 2 chunks); Q already scaled to log2 domain
    u16x8 qf_[2];
#pragma unroll
    for (int kc = 0; kc < 2; ++kc)
        qf_[kc] = *(const u16x8*)(qkv + (rowbase + qstart + qrow0 + (l & 15)) * 1536
                                  + hq * 64 + kc * 32 + (l >> 4) * 8);

    f32x4 o[4] = {};
    float mrow = -__builtin_inff(), srow_ = 0.f;

    const u16* kbase_ptr = qkv + 1024 + h * 64;
    const u16* vbase_ptr = vt + (size_t)((b * 4 + h) * 64) * 4096;

    // per-wave staging chunk (1 KiB each for K and V), pre-swizzled source
    int sb_ = w * 1024 + l * 16;
    int g_row = sb_ >> 7, g_inner = sb_ & 127;
    int g_col = (g_inner ^ ((g_row & 7) << 4)) >> 1;

#pragma unroll
    for (int kstart = qstart - 256; kstart <= qstart + 256; kstart += 64) {
        if (kstart < 0 || kstart >= 4096) continue;
        gload16(kbase_ptr + (rowbase + kstart + g_row) * 1536 + g_col, (char*)Ks + w * 1024);
        gload16(vbase_ptr + (size_t)g_row * 4096 + kstart + g_col, (char*)Vs + w * 1024);
        __syncthreads();

        // S^T[key][q] = K * Q^T  (log2-domain)
        f32x4 st[4] = {};
#pragma unroll
        for (int kc = 0; kc < 2; ++kc) {
            int co = (kc * 32 + (l >> 4) * 8) * 2;
#pragma unroll
            for (int kf = 0; kf < 4; ++kf) {
                int row = kf * 16 + (l & 15);
                u16x8 kfr = *(const u16x8*)((const char*)Ks + row * 128 + (co ^ ((row & 7) << 4)));
                st[kf] = mfma_bf16(kfr, qf_[kc], st[kf]);
            }
        }

        // window masking only needed on the two boundary tiles
        bool mlo = (kstart == qstart - 256);
        bool mhi = (kstart == qstart + 256);

        int qoff = qrow0 + (l & 15);
        float pmax = -1e30f;
        float sv[4][4];
#pragma unroll
        for (int kf = 0; kf < 4; ++kf)
#pragma unroll
            for (int r = 0; r < 4; r++) {
                int koff = kf * 16 + (l >> 4) * 4 + r;
                float v = st[kf][r];
                if (mlo && koff < qoff) v = -1e30f;
                if (mhi && koff > qoff) v = -1e30f;
                sv[kf][r] = v;
                pmax = fmaxf(pmax, v);
            }
        pmax = fmaxf(pmax, __shfl_xor(pmax, 16));
        pmax = fmaxf(pmax, __shfl_xor(pmax, 32));

        // defer-max: skip rescale when growth bounded (P then bounded by 2^8)
        bool resc = !__all(pmax - mrow <= 8.0f);
        float newm = resc ? fmaxf(mrow, pmax) : mrow;
        float psum = 0.f;
#pragma unroll
        for (int kf = 0; kf < 4; ++kf) {
            u16x4 pk;
#pragma unroll
            for (int r = 0; r < 4; r++) {
                float e = __builtin_amdgcn_exp2f(sv[kf][r] - newm);
                psum += e;
                pk[r] = pbf(e);
            }
            int row = l & 15;
            int keyc = kf * 16 + (l >> 4) * 4;
            *(u16x4*)((char*)Ps[w] + ((row * 128 + keyc * 2) ^ ((row & 7) << 4))) = pk;
        }
        psum += __shfl_xor(psum, 16);
        psum += __shfl_xor(psum, 32);
        if (resc) {
            float fs = __builtin_amdgcn_exp2f(mrow - newm);
            srow_ = srow_ * fs + psum;
            mrow = newm;
#pragma unroll
            for (int r = 0; r < 4; r++) {
                float fb = __shfl(fs, (l >> 4) * 4 + r);
#pragma unroll
                for (int nf = 0; nf < 4; ++nf) o[nf][r] *= fb;
            }
        } else {
            srow_ += psum;
        }

        // O += P * V
#pragma unroll
        for (int kc = 0; kc < 2; ++kc) {
            int co = (kc * 32 + (l >> 4) * 8) * 2;
            int prow = l & 15;
            u16x8 pa = *(const u16x8*)((const char*)Ps[w] + ((prow * 128 + co) ^ ((prow & 7) << 4)));
#pragma unroll
            for (int nf = 0; nf < 4; ++nf) {
                int row = nf * 16 + (l & 15);
                u16x8 vb = *(const u16x8*)((const char*)Vs + row * 128 + (co ^ ((row & 7) << 4)));
                o[nf] = mfma_bf16(pa, vb, o[nf]);
            }
        }
        __syncthreads();
    }

    // normalize + store y bf16 [8192][1024]
    float inv = 1.0f / srow_;
#pragma unroll
    for (int r = 0; r < 4; r++) {
        float sb = __shfl(inv, (l >> 4) * 4 + r);
        int row = qstart + qrow0 + (l >> 4) * 4 + r;
#pragma unroll
        for (int nf = 0; nf < 4; ++nf) {
            int col = hq * 64 + nf * 16 + (l & 15);
            y[(rowbase + row) * 1024 + col] = f2bf(o[nf][r] * sb);
        }
    }
}

// ---------------- host launch ----------------

extern "C" void kernel_launch(void* const* d_in, const int* in_sizes, int n_in,
                              void* d_out, int out_size, void* d_ws, size_t ws_size,
                              hipStream_t stream) {
    const float* x  = (const float*)d_in[0];
    const float* wq = (const float*)d_in[1];
    const float* bq = (const float*)d_in[2];
    const float* wk = (const float*)d_in[3];
    const float* bk = (const float*)d_in[4];
    const float* wv = (const float*)d_in[5];
    const float* bv = (const float*)d_in[6];
    const float* wo = (const float*)d_in[7];
    const float* bo = (const float*)d_in[8];
    float* out = (float*)d_out;

    char* p = (char*)d_ws;
    u16* xb     = (u16*)p;   p += (size_t)8192 * 1024 * 2;   // x bf16
    u16* wqkvt  = (u16*)p;   p += (size_t)1536 * 1024 * 2;   // [n][k] bf16 (q,k,v concat)
    u16* wot    = (u16*)p;   p += (size_t)1024 * 1024 * 2;   // wo^T bf16
    float* bqkv = (float*)p; p += 8192;                      // 1536 fp32 (padded)
    u16* qkvb   = (u16*)p;   p += (size_t)8192 * 1536 * 2;   // QKV bf16
    u16* vtb    = (u16*)p;   p += (size_t)512 * 4096 * 2;    // V^T bf16
    u16* yb     = (u16*)p;                                   // attn out bf16

    cvt_x_kernel<<<8192, 256, 0, stream>>>((const float4*)x, (u16x4*)xb);
    fill_bias<<<6, 256, 0, stream>>>(bq, bk, bv, bqkv);
    twt_kernel<<<dim3(16, 16), 256, 0, stream>>>(wq, wqkvt, 1024, 0);
    twt_kernel<<<dim3(16, 4),  256, 0, stream>>>(wk, wqkvt, 256, 1024);
    twt_kernel<<<dim3(16, 4),  256, 0, stream>>>(wv, wqkvt, 256, 1280);
    twt_kernel<<<dim3(16, 16), 256, 0, stream>>>(wo, wot, 1024, 0);

    // Q columns pre-scaled by 0.125*log2(e) so attention scores are in log2 domain
    gemm_bt<false><<<dim3(12, 64), 256, 0, stream>>>(xb, wqkvt, qkvb, bqkv,
                                                     8192, 1536, 1024, 1024, 0.18033688f);
    tv_kernel<<<dim3(64, 4, 2), 256, 0, stream>>>(qkvb, vtb);
    attn_kernel<<<dim3(64, 8, 2), 512, 0, stream>>>(qkvb, vtb, yb);
    gemm_bt<true><<<dim3(8, 64), 256, 0, stream>>>(yb, wot, out, bo,
                                                   8192, 1024, 1024, 0, 1.0f);
}